// Round 13
// baseline (316.578 us; speedup 1.0000x reference)
//
#include <hip/hip_runtime.h>
#include <hip/hip_bf16.h>

#define N_NODES 4096
#define DIM 768
#define NH 8
#define DH 96
#define NB 64
#define NL 2

typedef unsigned short ushort_t;
typedef __attribute__((ext_vector_type(8))) short bf16x8;
typedef __attribute__((ext_vector_type(4))) float f32x4;

typedef __attribute__((address_space(1))) const unsigned int gas_uint;
typedef __attribute__((address_space(3))) unsigned int las_uint;

__device__ inline float bf2f(unsigned int u16) {
    union { unsigned int i; float f; } v;
    v.i = u16 << 16;
    return v.f;
}
__device__ inline ushort_t f2bf(float f) {
    union { float f; unsigned int i; } v;
    v.f = f;
    unsigned int u = v.i;
    return (ushort_t)((u + 0x7fffu + ((u >> 16) & 1u)) >> 16);
}

// async global->LDS, 16B per lane; LDS dest is wave-uniform base + lane*16
__device__ inline void gld16(const ushort_t* g, const ushort_t* l) {
    __builtin_amdgcn_global_load_lds((gas_uint*)g, (las_uint*)l, 16, 0, 0);
}

// ---------------------------------------------------------------------------
// f32 -> (f32 copy, bf16 shadow), both sides in one dispatch (grid.y = side).
// Block (0, side=0) additionally computes the per-graph segment table.
// seg: [0..63]=s1, [64..127]=e1, [128..191]=s2, [192..255]=e2
// ---------------------------------------------------------------------------
__global__ __launch_bounds__(256) void cast_in2(const float* __restrict__ s1,
                                                const float* __restrict__ s2,
                                                float* __restrict__ d1,
                                                float* __restrict__ d2,
                                                ushort_t* __restrict__ db1,
                                                ushort_t* __restrict__ db2,
                                                const int* __restrict__ bt1,
                                                const int* __restrict__ bt2,
                                                int* __restrict__ seg) {
    int side = blockIdx.y;
    const float* src = side ? s2 : s1;
    float* dst = side ? d2 : d1;
    ushort_t* dstb = side ? db2 : db1;
    int tid = threadIdx.x;
    int i = blockIdx.x * 256 + tid;
    float4 v = ((const float4*)src)[i];
    ((float4*)dst)[i] = v;
    uint2 p;
    p.x = (unsigned)f2bf(v.x) | ((unsigned)f2bf(v.y) << 16);
    p.y = (unsigned)f2bf(v.z) | ((unsigned)f2bf(v.w) << 16);
    ((uint2*)dstb)[i] = p;
    if (blockIdx.x == 0 && side == 0 && tid < 128) {
        const int* arr = (tid < 64) ? bt1 : bt2;
        int b = tid & 63;
        int base = (tid < 64) ? 0 : 128;
        int lo = 0, hi = N_NODES;
        while (lo < hi) { int mid = (lo + hi) >> 1; if (arr[mid] < b) lo = mid + 1; else hi = mid; }
        int s = lo;
        hi = N_NODES;
        while (lo < hi) { int mid = (lo + hi) >> 1; if (arr[mid] < b + 1) lo = mid + 1; else hi = mid; }
        seg[base + b] = s;
        seg[base + 64 + b] = lo;
    }
}

// ---------------------------------------------------------------------------
// Weight transpose+cast, all 8 matrices in one dispatch (grid.z = matrix).
// W[k][n] f32 -> Wt[n][k] bf16 (768x768 each).  z==8: mW1 f32->bf16
// elementwise (1536x768, 2 float4-chunks per thread, no transpose).
// ---------------------------------------------------------------------------
__global__ __launch_bounds__(256) void wtcast_all(const float* __restrict__ Wq,
                                                  const float* __restrict__ Wk,
                                                  const float* __restrict__ Wv,
                                                  const float* __restrict__ Wo,
                                                  ushort_t* __restrict__ Wbt,
                                                  const float* __restrict__ mW1,
                                                  ushort_t* __restrict__ W1b) {
    int z = blockIdx.z;             // 0..8
    int tid = threadIdx.x;
    if (z == 8) {
        int bidx = blockIdx.y * 24 + blockIdx.x;    // 0..575
#pragma unroll
        for (int rep = 0; rep < 2; ++rep) {
            int i = (bidx + rep * 576) * 256 + tid;  // < 294912
            float4 v = ((const float4*)mW1)[i];
            uint2 p;
            p.x = (unsigned)f2bf(v.x) | ((unsigned)f2bf(v.y) << 16);
            p.y = (unsigned)f2bf(v.z) | ((unsigned)f2bf(v.w) << 16);
            ((uint2*)W1b)[i] = p;
        }
        return;
    }
    __shared__ float t[32][33];
    int which = z >> 1, l = z & 1;
    const float* W = (which == 0) ? Wq : (which == 1) ? Wk : (which == 2) ? Wv : Wo;
    W += (size_t)l * DIM * DIM;
    ushort_t* Wt = Wbt + (size_t)(which * NL + l) * DIM * DIM;
    int tx = tid & 31, ty = tid >> 5;  // 32 x 8
    int k0 = blockIdx.x * 32, n0 = blockIdx.y * 32;
#pragma unroll
    for (int i = 0; i < 4; ++i)
        t[ty + 8 * i][tx] = W[(size_t)(k0 + ty + 8 * i) * DIM + n0 + tx];
    __syncthreads();
#pragma unroll
    for (int i = 0; i < 4; ++i)
        Wt[(size_t)(n0 + ty + 8 * i) * DIM + k0 + tx] = f2bf(t[tx][ty + 8 * i]);
}

// ---------------------------------------------------------------------------
// bf16 MFMA GEMM, BK=64 (refchecked r8/r10/r12): global_load_lds(16B)
// staging, linear LDS rows of 64 bf16 (128B = 8 slots of 16B), both-sides
// XOR swizzle slot ^= (row&7) [rule #21].
// BM=128: 4 waves 2x2, per-wave 64x64 (acc 4x4).  Tile N always 128.
// BM=64 : 4 waves 1x4, per-wave 64x32 (acc 4x2).
// NEW r13: bf16-out epilogue stages the C-tile in LDS (pad 136) and emits
// fully-coalesced 256B row segments (fixes r8's measured 2x WRITE_SIZE
// amplification from strided 32B bf16 scatters). f32 path unchanged.
// ---------------------------------------------------------------------------
template <int BM, int OUT_BF16>
__device__ inline void gemm_body(const ushort_t* __restrict__ X,
                                 const ushort_t* __restrict__ W,
                                 const float* __restrict__ bias,
                                 ushort_t* __restrict__ outB,
                                 float* __restrict__ outF,
                                 int brow, int bcol) {
    constexpr int STAGE = BM * 64 + 128 * 64;
    constexpr int CTILE = OUT_BF16 ? BM * 136 : 0;
    constexpr int SMEMN = (STAGE > CTILE) ? STAGE : CTILE;
    __shared__ alignas(16) ushort_t SMEM[SMEMN];
    ushort_t* As = SMEM;
    ushort_t* Bs = SMEM + BM * 64;
    constexpr int NJ = (BM == 128) ? 4 : 2;   // n-fragments per wave
    constexpr int AROWS = BM / 4;             // A rows staged per wave
    int tid = threadIdx.x;
    int lane = tid & 63, wid = tid >> 6;
    int WR = (BM == 128) ? (wid >> 1) : 0;
    int WC = (BM == 128) ? (wid & 1) : wid;

    f32x4 acc[4][NJ];
#pragma unroll
    for (int m = 0; m < 4; ++m)
#pragma unroll
        for (int n = 0; n < NJ; ++n)
            acc[m][n] = (f32x4){0.f, 0.f, 0.f, 0.f};

    int srow = lane >> 3;                       // 0..7
    int sslot = (lane & 7) ^ srow;              // logical k-slot to fetch
    int aRow0 = wid * AROWS;
    const ushort_t* aS = X + (size_t)(brow + aRow0 + srow) * DIM + sslot * 8;
    const ushort_t* bS = W + (size_t)(bcol + wid * 32 + srow) * DIM + sslot * 8;
    const ushort_t* ldsA = As + aRow0 * 64;
    const ushort_t* ldsB = Bs + wid * 32 * 64;

    int fr = lane & 15;
    int u = lane >> 4;
    const char* Ab = (const char*)As;
    const char* Bb = (const char*)Bs;

    for (int kc = 0; kc < DIM; kc += 64) {
        __syncthreads();
#pragma unroll
        for (int t = 0; t < AROWS / 8; ++t)
            gld16(aS + kc + (size_t)(8 * t) * DIM, ldsA + (8 * t) * 64);
#pragma unroll
        for (int t = 0; t < 4; ++t)
            gld16(bS + kc + (size_t)(8 * t) * DIM, ldsB + (8 * t) * 64);
        __syncthreads();
#pragma unroll
        for (int kk = 0; kk < 2; ++kk) {
            int slot = (kk * 4 + u) ^ (fr & 7);
            bf16x8 af[4], bfr[NJ];
#pragma unroll
            for (int m = 0; m < 4; ++m)
                af[m] = *(const bf16x8*)(Ab + (size_t)(WR * 64 + m * 16 + fr) * 128 + slot * 16);
#pragma unroll
            for (int n = 0; n < NJ; ++n)
                bfr[n] = *(const bf16x8*)(Bb + (size_t)(WC * (16 * NJ) + n * 16 + fr) * 128 + slot * 16);
#pragma unroll
            for (int m = 0; m < 4; ++m)
#pragma unroll
                for (int n = 0; n < NJ; ++n)
                    acc[m][n] = __builtin_amdgcn_mfma_f32_16x16x32_bf16(af[m], bfr[n], acc[m][n], 0, 0, 0);
        }
    }

    if (OUT_BF16) {
        // stage C tile (bf16) to LDS, then coalesced 256B row writes
        __syncthreads();
#pragma unroll
        for (int m = 0; m < 4; ++m)
#pragma unroll
            for (int n = 0; n < NJ; ++n) {
                int col = WC * (16 * NJ) + n * 16 + fr;
                float bv = bias[bcol + col];
#pragma unroll
                for (int j = 0; j < 4; ++j) {
                    int row = WR * 64 + m * 16 + u * 4 + j;
                    SMEM[(size_t)row * 136 + col] = f2bf(acc[m][n][j] + bv);
                }
            }
        __syncthreads();
#pragma unroll
        for (int r = 0; r < BM / 16; ++r) {
            int idx = r * 256 + tid;
            int row = idx >> 4, cq = idx & 15;
            *(uint4*)(outB + (size_t)(brow + row) * DIM + bcol + cq * 8) =
                *(const uint4*)(SMEM + (size_t)row * 136 + cq * 8);
        }
    } else {
#pragma unroll
        for (int m = 0; m < 4; ++m)
#pragma unroll
            for (int n = 0; n < NJ; ++n) {
                int col = bcol + WC * (16 * NJ) + n * 16 + fr;
                float bv = bias[col];
#pragma unroll
                for (int j = 0; j < 4; ++j) {
                    int row = brow + WR * 64 + m * 16 + u * 4 + j;
                    outF[(size_t)row * DIM + col] = acc[m][n][j] + bv;
                }
            }
    }
}

struct QKVArgs {
    const ushort_t* Xq;
    const ushort_t* Xkv;
    const ushort_t* W0; const ushort_t* W1; const ushort_t* W2;
    const float* b0; const float* b1; const float* b2;
    ushort_t* O0; ushort_t* O1; ushort_t* O2;
};

__global__ __launch_bounds__(256, 3) void qkv_gemm(QKVArgs a) {
    int z = blockIdx.z;
    const ushort_t* X = (z == 0) ? a.Xq : a.Xkv;
    const ushort_t* W = (z == 0) ? a.W0 : (z == 1) ? a.W1 : a.W2;
    const float* b = (z == 0) ? a.b0 : (z == 1) ? a.b1 : a.b2;
    ushort_t* O = (z == 0) ? a.O0 : (z == 1) ? a.O1 : a.O2;
    gemm_body<128, 1>(X, W, b, O, nullptr, blockIdx.x * 128, blockIdx.y * 128);
}

__global__ __launch_bounds__(256, 3) void o_gemm(const ushort_t* __restrict__ X,
                                                 const ushort_t* __restrict__ W,
                                                 const float* __restrict__ b,
                                                 float* __restrict__ Out) {
    gemm_body<64, 0>(X, W, b, nullptr, Out, blockIdx.x * 64, blockIdx.y * 128);
}

// ---------------------------------------------------------------------------
// MFMA segment attention. Grid (64 graphs, 8 heads), 4 waves per block.
// ---------------------------------------------------------------------------
#define MAXSEG 192
#define NKP 200   // padded key stride (elements); 400B rows -> ~2-way conflicts
__global__ __launch_bounds__(256) void attn_mfma(const ushort_t* __restrict__ Q,
                                                 const ushort_t* __restrict__ K,
                                                 const ushort_t* __restrict__ V,
                                                 ushort_t* __restrict__ M,
                                                 const int* __restrict__ seg,
                                                 int qbase, int kvbase) {
    __shared__ alignas(16) ushort_t VT[96 * NKP];        // V^T [dim][key]
    __shared__ alignas(16) ushort_t PL[4 * 16 * NKP];    // per-wave P [q][key]
    int b = blockIdx.x, h = blockIdx.y;
    int tid = threadIdx.x, lane = tid & 63, wid = tid >> 6;
    int qs = seg[qbase + b], qe = seg[qbase + 64 + b];
    int ks = seg[kvbase + b], ke = seg[kvbase + 64 + b];
    int nq = qe - qs, nk = ke - ks;
    if (nq <= 0) return;
    if (nk > MAXSEG) nk = MAXSEG;
    if (nk <= 0) {  // not expected for this dataset; zero the head slice
        for (int q = qs + wid; q < qe; q += 4)
            for (int c = lane; c < DH; c += 64)
                M[(size_t)q * DIM + h * DH + c] = 0;
        return;
    }
    int nkp32 = (nk + 31) & ~31;
    int nkt = nkp32 >> 4;   // 16-key score tiles
    int nk2 = nkp32 >> 5;   // 32-key PV steps

    // ---- stage V^T (zero-fill padded keys so 0*garbage can't be NaN) ----
    for (int idx = tid; idx < nkp32 * 12; idx += 256) {
        int j = idx / 12, c = idx - j * 12;     // key j, dim-octet c
        ushort_t tmp[8];
        if (j < nk) {
            *(uint4*)tmp = *(const uint4*)(V + (size_t)(ks + j) * DIM + h * DH + c * 8);
        } else {
#pragma unroll
            for (int r = 0; r < 8; ++r) tmp[r] = 0;
        }
#pragma unroll
        for (int r = 0; r < 8; ++r)
            VT[(size_t)(c * 8 + r) * NKP + j] = tmp[r];
    }
    __syncthreads();

    const float scale = 0.1020620726159658f;  // 1/sqrt(96)
    int fr = lane & 15;
    int koff = (lane >> 4) * 8;
    ushort_t* pl = PL + (size_t)wid * 16 * NKP;

    for (int qt = wid; qt * 16 < nq; qt += 4) {
        // ---- A-fragments of Q (clamped rows; masked at store) ----
        int qrow = qs + qt * 16 + fr;
        if (qrow > qe - 1) qrow = qe - 1;
        const ushort_t* qp = Q + (size_t)qrow * DIM + h * DH + koff;
        bf16x8 af0 = *(const bf16x8*)(qp);
        bf16x8 af1 = *(const bf16x8*)(qp + 32);
        bf16x8 af2 = *(const bf16x8*)(qp + 64);

        // ---- scores ----
        f32x4 sc[12];
#pragma unroll
        for (int kt = 0; kt < 12; ++kt) {
            if (kt >= nkt) continue;
            int key = ks + kt * 16 + fr;
            if (key > ke - 1) key = ke - 1;
            const ushort_t* kp = K + (size_t)key * DIM + h * DH + koff;
            f32x4 a = (f32x4){0.f, 0.f, 0.f, 0.f};
            a = __builtin_amdgcn_mfma_f32_16x16x32_bf16(af0, *(const bf16x8*)(kp), a, 0, 0, 0);
            a = __builtin_amdgcn_mfma_f32_16x16x32_bf16(af1, *(const bf16x8*)(kp + 32), a, 0, 0, 0);
            a = __builtin_amdgcn_mfma_f32_16x16x32_bf16(af2, *(const bf16x8*)(kp + 64), a, 0, 0, 0);
            sc[kt] = a;
        }

        // ---- softmax over keys (reduce across lane&15 within groups) ----
        float mrow[4] = {-1e30f, -1e30f, -1e30f, -1e30f};
#pragma unroll
        for (int kt = 0; kt < 12; ++kt) {
            if (kt >= nkt) continue;
            bool valid = (kt * 16 + fr) < nk;
#pragma unroll
            for (int j = 0; j < 4; ++j) {
                float s = valid ? sc[kt][j] * scale : -1e30f;
                sc[kt][j] = s;
                mrow[j] = fmaxf(mrow[j], s);
            }
        }
#pragma unroll
        for (int j = 0; j < 4; ++j) {
            mrow[j] = fmaxf(mrow[j], __shfl_xor(mrow[j], 1, 64));
            mrow[j] = fmaxf(mrow[j], __shfl_xor(mrow[j], 2, 64));
            mrow[j] = fmaxf(mrow[j], __shfl_xor(mrow[j], 4, 64));
            mrow[j] = fmaxf(mrow[j], __shfl_xor(mrow[j], 8, 64));
        }
        float rsum[4] = {0.f, 0.f, 0.f, 0.f};
#pragma unroll
        for (int kt = 0; kt < 12; ++kt) {
            if (kt >= nkt) continue;
#pragma unroll
            for (int j = 0; j < 4; ++j) {
                float p = __expf(sc[kt][j] - mrow[j]);
                sc[kt][j] = p;
                rsum[j] += p;
            }
        }
#pragma unroll
        for (int j = 0; j < 4; ++j) {
            rsum[j] += __shfl_xor(rsum[j], 1, 64);
            rsum[j] += __shfl_xor(rsum[j], 2, 64);
            rsum[j] += __shfl_xor(rsum[j], 4, 64);
            rsum[j] += __shfl_xor(rsum[j], 8, 64);
        }
        float rinv[4];
#pragma unroll
        for (int j = 0; j < 4; ++j) rinv[j] = 1.f / rsum[j];

        // ---- write P (bf16) to this wave's LDS tile ----
#pragma unroll
        for (int kt = 0; kt < 12; ++kt) {
            if (kt >= nkt) continue;
#pragma unroll
            for (int j = 0; j < 4; ++j)
                pl[(size_t)((lane >> 4) * 4 + j) * NKP + kt * 16 + fr] = f2bf(sc[kt][j]);
        }

        // ---- PV: out[q][d] tiles via MFMA, A from P_lds, B from VT ----
        f32x4 oacc[6];
#pragma unroll
        for (int nt = 0; nt < 6; ++nt) oacc[nt] = (f32x4){0.f, 0.f, 0.f, 0.f};
#pragma unroll
        for (int k2 = 0; k2 < 6; ++k2) {
            if (k2 >= nk2) continue;
            bf16x8 pa = *(const bf16x8*)(pl + (size_t)fr * NKP + k2 * 32 + koff);
#pragma unroll
            for (int nt = 0; nt < 6; ++nt) {
                bf16x8 vb = *(const bf16x8*)(VT + (size_t)(nt * 16 + fr) * NKP + k2 * 32 + koff);
                oacc[nt] = __builtin_amdgcn_mfma_f32_16x16x32_bf16(pa, vb, oacc[nt], 0, 0, 0);
            }
        }

        // ---- store head slice of M ----
#pragma unroll
        for (int nt = 0; nt < 6; ++nt)
#pragma unroll
            for (int j = 0; j < 4; ++j) {
                int qr = qt * 16 + (lane >> 4) * 4 + j;
                if (qr < nq)
                    M[(size_t)(qs + qr) * DIM + h * DH + nt * 16 + fr] = f2bf(oacc[nt][j] * rinv[j]);
            }
    }
}

// ---------------------------------------------------------------------------
// h = LayerNorm(h + o) * g + b  (in-place f32) + bf16 shadow
// One WAVE per row (4 rows/block), float4 loads, shfl-only reduce, no LDS.
// ---------------------------------------------------------------------------
__global__ __launch_bounds__(256) void add_ln_kernel(float* __restrict__ h,
                                                     ushort_t* __restrict__ hb,
                                                     const float* __restrict__ o,
                                                     const float* __restrict__ g,
                                                     const float* __restrict__ bb) {
    int row = blockIdx.x * 4 + (threadIdx.x >> 6);
    int lane = threadIdx.x & 63;
    float* hp = h + (size_t)row * DIM;
    const float* op = o + (size_t)row * DIM;
    float x[12];
    float s = 0.f, s2 = 0.f;
#pragma unroll
    for (int k = 0; k < 3; ++k) {
        int c = lane * 4 + k * 256;
        float4 a = *(const float4*)(hp + c);
        float4 bv = *(const float4*)(op + c);
        float v0 = a.x + bv.x, v1 = a.y + bv.y, v2 = a.z + bv.z, v3 = a.w + bv.w;
        x[4 * k + 0] = v0; x[4 * k + 1] = v1; x[4 * k + 2] = v2; x[4 * k + 3] = v3;
        s += (v0 + v1) + (v2 + v3);
        s2 += v0 * v0 + v1 * v1 + v2 * v2 + v3 * v3;
    }
#pragma unroll
    for (int off = 32; off; off >>= 1) {
        s += __shfl_xor(s, off, 64);
        s2 += __shfl_xor(s2, off, 64);
    }
    float mu = s * (1.f / 768.f);
    float var = s2 * (1.f / 768.f) - mu * mu;
    float rstd = rsqrtf(var + 1e-5f);
#pragma unroll
    for (int k = 0; k < 3; ++k) {
        int c = lane * 4 + k * 256;
        float4 gv = *(const float4*)(g + c);
        float4 bv = *(const float4*)(bb + c);
        float4 y;
        y.x = (x[4 * k + 0] - mu) * rstd * gv.x + bv.x;
        y.y = (x[4 * k + 1] - mu) * rstd * gv.y + bv.y;
        y.z = (x[4 * k + 2] - mu) * rstd * gv.z + bv.z;
        y.w = (x[4 * k + 3] - mu) * rstd * gv.w + bv.w;
        *(float4*)(hp + c) = y;
        uint2 p;
        p.x = (unsigned)f2bf(y.x) | ((unsigned)f2bf(y.y) << 16);
        p.y = (unsigned)f2bf(y.z) | ((unsigned)f2bf(y.w) << 16);
        *(uint2*)(hb + (size_t)row * DIM + c) = p;
    }
}

// ---------------------------------------------------------------------------
// Per-graph mean+max aggregate -> G[B, 1536]
// ---------------------------------------------------------------------------
__global__ __launch_bounds__(256) void agg_kernel(const float* __restrict__ h1,
                                                  const float* __restrict__ h2,
                                                  const int* __restrict__ seg,
                                                  float* __restrict__ G) {
    int b = blockIdx.x, side = blockIdx.y;
    int c = blockIdx.z * 256 + threadIdx.x;
    const float* hp = side ? h2 : h1;
    int s = seg[side * 128 + b], e = seg[side * 128 + 64 + b];
    int cnt = e - s;
    float sum = 0.f, mx = -1e30f;
    int i = s;
    for (; i + 4 <= e; i += 4) {
        float v0 = hp[(size_t)(i + 0) * DIM + c];
        float v1 = hp[(size_t)(i + 1) * DIM + c];
        float v2 = hp[(size_t)(i + 2) * DIM + c];
        float v3 = hp[(size_t)(i + 3) * DIM + c];
        sum += v0 + v1 + v2 + v3;
        mx = fmaxf(fmaxf(mx, fmaxf(v0, v1)), fmaxf(v2, v3));
    }
    for (; i < e; ++i) {
        float v = hp[(size_t)i * DIM + c];
        sum += v;
        mx = fmaxf(mx, v);
    }
    G[(size_t)b * 1536 + side * DIM + c] = (cnt > 0) ? (sum / (float)cnt + mx) : 0.f;
}

// ---------------------------------------------------------------------------
// Hid[b,j] = relu(G[b,:] @ W1[:,j] + b1[j]),  W1 in bf16.
// grid (16 b-groups of 4, 6 j-chunks of 128). Thread owns a j-quad
// (bf16x4 = 8B loads); 4 graphs amortize each W1 read; 8 waves k-split
// (192 each) + padded LDS reduce. 96 blocks, W1b traffic 37 MB total.
// ---------------------------------------------------------------------------
__global__ __launch_bounds__(256) void mlp1_kernel(const float* __restrict__ G,
                                                   const ushort_t* __restrict__ W1b,
                                                   const float* __restrict__ b1,
                                                   float* __restrict__ Hid) {
    __shared__ float gs[4][1536];
    __shared__ float red[7][32][17];    // [kq-1][jq][16 vals + pad]
    int bg = blockIdx.x;                // graphs bg*4 .. bg*4+3
    int jc = blockIdx.y;                // j chunk of 128
    int tid = threadIdx.x;
    int jq = tid & 31;                  // j-quad within chunk
    int kq = tid >> 5;                  // k eighth (192 rows)
    int j = jc * 128 + jq * 4;

    for (int idx = tid; idx < 4 * 1536 / 4; idx += 256)
        ((float4*)&gs[0][0])[idx] = ((const float4*)(G + (size_t)bg * 4 * 1536))[idx];
    __syncthreads();

    float acc[4][4] = {};
    const ushort_t* wp = W1b + (size_t)(kq * 192) * DIM + j;
    for (int i = 0; i < 192; ++i) {
        uint2 w = *(const uint2*)(wp + (size_t)i * DIM);
        float w0 = bf2f(w.x & 0xffffu), w1 = bf2f(w.x >> 16);
        float w2 = bf2f(w.y & 0xffffu), w3 = bf2f(w.y >> 16);
        int krow = kq * 192 + i;
#pragma unroll
        for (int bb = 0; bb < 4; ++bb) {
            float gv = gs[bb][krow];
            acc[bb][0] += gv * w0; acc[bb][1] += gv * w1;
            acc[bb][2] += gv * w2; acc[bb][3] += gv * w3;
        }
    }
    if (kq) {
#pragma unroll
        for (int bb = 0; bb < 4; ++bb)
#pragma unroll
            for (int c = 0; c < 4; ++c)
                red[kq - 1][jq][bb * 4 + c] = acc[bb][c];
    }
    __syncthreads();
    if (kq == 0) {
        float4 bv = *(const float4*)(b1 + j);
#pragma unroll
        for (int bb = 0; bb < 4; ++bb) {
            float r[4];
#pragma unroll
            for (int c = 0; c < 4; ++c) {
                r[c] = acc[bb][c];
#pragma unroll
                for (int q = 0; q < 7; ++q) r[c] += red[q][jq][bb * 4 + c];
            }
            float4 o;
            o.x = fmaxf(r[0] + bv.x, 0.f);
            o.y = fmaxf(r[1] + bv.y, 0.f);
            o.z = fmaxf(r[2] + bv.z, 0.f);
            o.w = fmaxf(r[3] + bv.w, 0.f);
            *(float4*)(Hid + (size_t)(bg * 4 + bb) * DIM + j) = o;
        }
    }
}

__global__ __launch_bounds__(256) void mlp2_kernel(const float* __restrict__ Hid,
                                                   const float* __restrict__ W2,
                                                   const float* __restrict__ b2,
                                                   float* __restrict__ out) {
    int b = blockIdx.x, tid = threadIdx.x;
    float s = 0.f;
    for (int j = tid; j < DIM; j += 256) s += Hid[(size_t)b * DIM + j] * W2[j];
#pragma unroll
    for (int off = 32; off; off >>= 1) s += __shfl_xor(s, off, 64);
    __shared__ float rs[4];
    if ((tid & 63) == 0) rs[tid >> 6] = s;
    __syncthreads();
    if (tid == 0) {
        float t = rs[0] + rs[1] + rs[2] + rs[3] + b2[0];
        out[b] = 1.f / (1.f + expf(-t));
    }
}

// ---------------------------------------------------------------------------
extern "C" void kernel_launch(void* const* d_in, const int* in_sizes, int n_in,
                              void* d_out, int out_size, void* d_ws, size_t ws_size,
                              hipStream_t stream) {
    const float* h1 = (const float*)d_in[0];
    const float* h2 = (const float*)d_in[1];
    const int* batch1 = (const int*)d_in[2];
    const int* batch2 = (const int*)d_in[3];
    const float* Wq = (const float*)d_in[4];
    const float* bq = (const float*)d_in[5];
    const float* Wk = (const float*)d_in[6];
    const float* bk = (const float*)d_in[7];
    const float* Wv = (const float*)d_in[8];
    const float* bv = (const float*)d_in[9];
    const float* Wo = (const float*)d_in[10];
    const float* bo = (const float*)d_in[11];
    const float* ln_g = (const float*)d_in[12];
    const float* ln_b = (const float*)d_in[13];
    const float* mW1 = (const float*)d_in[14];
    const float* mb1 = (const float*)d_in[15];
    const float* mW2 = (const float*)d_in[16];
    const float* mb2 = (const float*)d_in[17];
    float* out = (float*)d_out;

    const size_t ND = (size_t)N_NODES * DIM;        // 3145728
    const size_t WSZ = (size_t)DIM * DIM;           // 589824
    float* h1c = (float*)d_ws;
    float* h2c = h1c + ND;
    float* G = h2c + ND;
    float* Hid = G + 64 * 1536;
    ushort_t* h1b = (ushort_t*)(Hid + 64 * DIM);
    ushort_t* h2b = h1b + ND;
    ushort_t* Qb = h2b + ND;
    ushort_t* Kb = Qb + ND;
    ushort_t* Vb = Kb + ND;
    ushort_t* Mbb = Vb + ND;
    ushort_t* Wbt = Mbb + ND;                       // 8 matrices [N][K]
    ushort_t* W1bf = Wbt + 8 * WSZ;                 // mW1 bf16 [1536][768]
    int* seg = (int*)(W1bf + (size_t)1536 * DIM);
    float* Ob = (float*)Qb;  // aliases Qb+Kb (both dead when O-proj runs)

    cast_in2<<<dim3((int)(ND / 4 / 256), 2), 256, 0, stream>>>(h1, h2, h1c, h2c, h1b, h2b,
                                                               batch1, batch2, seg);
    wtcast_all<<<dim3(24, 24, 9), 256, 0, stream>>>(Wq, Wk, Wv, Wo, Wbt, mW1, W1bf);

    dim3 qkvg(32, 6, 3), og(64, 6), ag(64, 8);
    for (int i = 0; i < NL; ++i) {
        const ushort_t* wtq = Wbt + (0 * NL + i) * WSZ;
        const ushort_t* wtk = Wbt + (1 * NL + i) * WSZ;
        const ushort_t* wtv = Wbt + (2 * NL + i) * WSZ;
        const ushort_t* wto = Wbt + (3 * NL + i) * WSZ;
        const float* bqi = bq + (size_t)i * DIM;
        const float* bki = bk + (size_t)i * DIM;
        const float* bvi = bv + (size_t)i * DIM;
        const float* boi = bo + (size_t)i * DIM;

        // direction 1: queries h1, keys/values h2
        QKVArgs a1 = {h1b, h2b, wtq, wtk, wtv, bqi, bki, bvi, Qb, Kb, Vb};
        qkv_gemm<<<qkvg, 256, 0, stream>>>(a1);
        attn_mfma<<<ag, 256, 0, stream>>>(Qb, Kb, Vb, Mbb, seg, 0, 128);
        o_gemm<<<og, 256, 0, stream>>>(Mbb, wto, boi, Ob);
        add_ln_kernel<<<N_NODES / 4, 256, 0, stream>>>(h1c, h1b, Ob,
                                                       ln_g + (size_t)(2 * i) * DIM,
                                                       ln_b + (size_t)(2 * i) * DIM);

        // direction 2: queries h2, keys/values h1 (updated)
        QKVArgs a2 = {h2b, h1b, wtq, wtk, wtv, bqi, bki, bvi, Qb, Kb, Vb};
        qkv_gemm<<<qkvg, 256, 0, stream>>>(a2);
        attn_mfma<<<ag, 256, 0, stream>>>(Qb, Kb, Vb, Mbb, seg, 128, 0);
        o_gemm<<<og, 256, 0, stream>>>(Mbb, wto, boi, Ob);
        add_ln_kernel<<<N_NODES / 4, 256, 0, stream>>>(h2c, h2b, Ob,
                                                       ln_g + (size_t)(2 * i + 1) * DIM,
                                                       ln_b + (size_t)(2 * i + 1) * DIM);
    }
    agg_kernel<<<dim3(64, 2, 3), 256, 0, stream>>>(h1c, h2c, seg, G);
    mlp1_kernel<<<dim3(16, 6), 256, 0, stream>>>(G, W1bf, mb1, Hid);
    mlp2_kernel<<<64, 256, 0, stream>>>(Hid, mW2, mb2, out);
}

// Round 14
// 311.977 us; speedup vs baseline: 1.0147x; 1.0147x over previous
//
#include <hip/hip_runtime.h>
#include <hip/hip_bf16.h>

#define N_NODES 4096
#define DIM 768
#define NH 8
#define DH 96
#define NB 64
#define NL 2

typedef unsigned short ushort_t;
typedef __attribute__((ext_vector_type(8))) short bf16x8;
typedef __attribute__((ext_vector_type(4))) float f32x4;

typedef __attribute__((address_space(1))) const unsigned int gas_uint;
typedef __attribute__((address_space(3))) unsigned int las_uint;

__device__ inline float bf2f(unsigned int u16) {
    union { unsigned int i; float f; } v;
    v.i = u16 << 16;
    return v.f;
}
__device__ inline ushort_t f2bf(float f) {
    union { float f; unsigned int i; } v;
    v.f = f;
    unsigned int u = v.i;
    return (ushort_t)((u + 0x7fffu + ((u >> 16) & 1u)) >> 16);
}

// async global->LDS, 16B per lane; LDS dest is wave-uniform base + lane*16
__device__ inline void gld16(const ushort_t* g, const ushort_t* l) {
    __builtin_amdgcn_global_load_lds((gas_uint*)g, (las_uint*)l, 16, 0, 0);
}

// ---------------------------------------------------------------------------
// f32 -> (f32 copy, bf16 shadow), both sides in one dispatch (grid.y = side).
// Block (0, side=0) additionally computes the per-graph segment table.
// seg: [0..63]=s1, [64..127]=e1, [128..191]=s2, [192..255]=e2
// ---------------------------------------------------------------------------
__global__ __launch_bounds__(256) void cast_in2(const float* __restrict__ s1,
                                                const float* __restrict__ s2,
                                                float* __restrict__ d1,
                                                float* __restrict__ d2,
                                                ushort_t* __restrict__ db1,
                                                ushort_t* __restrict__ db2,
                                                const int* __restrict__ bt1,
                                                const int* __restrict__ bt2,
                                                int* __restrict__ seg) {
    int side = blockIdx.y;
    const float* src = side ? s2 : s1;
    float* dst = side ? d2 : d1;
    ushort_t* dstb = side ? db2 : db1;
    int tid = threadIdx.x;
    int i = blockIdx.x * 256 + tid;
    float4 v = ((const float4*)src)[i];
    ((float4*)dst)[i] = v;
    uint2 p;
    p.x = (unsigned)f2bf(v.x) | ((unsigned)f2bf(v.y) << 16);
    p.y = (unsigned)f2bf(v.z) | ((unsigned)f2bf(v.w) << 16);
    ((uint2*)dstb)[i] = p;
    if (blockIdx.x == 0 && side == 0 && tid < 128) {
        const int* arr = (tid < 64) ? bt1 : bt2;
        int b = tid & 63;
        int base = (tid < 64) ? 0 : 128;
        int lo = 0, hi = N_NODES;
        while (lo < hi) { int mid = (lo + hi) >> 1; if (arr[mid] < b) lo = mid + 1; else hi = mid; }
        int s = lo;
        hi = N_NODES;
        while (lo < hi) { int mid = (lo + hi) >> 1; if (arr[mid] < b + 1) lo = mid + 1; else hi = mid; }
        seg[base + b] = s;
        seg[base + 64 + b] = lo;
    }
}

// ---------------------------------------------------------------------------
// Weight transpose+cast, all 8 matrices in one dispatch (grid.z = matrix).
// W[k][n] f32 -> Wt[n][k] bf16 (768x768 each).  z==8: mW1 f32->bf16
// elementwise (1536x768, 2 float4-chunks per thread, no transpose).
// ---------------------------------------------------------------------------
__global__ __launch_bounds__(256) void wtcast_all(const float* __restrict__ Wq,
                                                  const float* __restrict__ Wk,
                                                  const float* __restrict__ Wv,
                                                  const float* __restrict__ Wo,
                                                  ushort_t* __restrict__ Wbt,
                                                  const float* __restrict__ mW1,
                                                  ushort_t* __restrict__ W1b) {
    int z = blockIdx.z;             // 0..8
    int tid = threadIdx.x;
    if (z == 8) {
        int bidx = blockIdx.y * 24 + blockIdx.x;    // 0..575
#pragma unroll
        for (int rep = 0; rep < 2; ++rep) {
            int i = (bidx + rep * 576) * 256 + tid;  // < 294912
            float4 v = ((const float4*)mW1)[i];
            uint2 p;
            p.x = (unsigned)f2bf(v.x) | ((unsigned)f2bf(v.y) << 16);
            p.y = (unsigned)f2bf(v.z) | ((unsigned)f2bf(v.w) << 16);
            ((uint2*)W1b)[i] = p;
        }
        return;
    }
    __shared__ float t[32][33];
    int which = z >> 1, l = z & 1;
    const float* W = (which == 0) ? Wq : (which == 1) ? Wk : (which == 2) ? Wv : Wo;
    W += (size_t)l * DIM * DIM;
    ushort_t* Wt = Wbt + (size_t)(which * NL + l) * DIM * DIM;
    int tx = tid & 31, ty = tid >> 5;  // 32 x 8
    int k0 = blockIdx.x * 32, n0 = blockIdx.y * 32;
#pragma unroll
    for (int i = 0; i < 4; ++i)
        t[ty + 8 * i][tx] = W[(size_t)(k0 + ty + 8 * i) * DIM + n0 + tx];
    __syncthreads();
#pragma unroll
    for (int i = 0; i < 4; ++i)
        Wt[(size_t)(n0 + ty + 8 * i) * DIM + k0 + tx] = f2bf(t[tx][ty + 8 * i]);
}

// ---------------------------------------------------------------------------
// bf16 MFMA GEMM, BK=64 (refchecked r8/r10/r12): global_load_lds(16B)
// staging, linear LDS rows of 64 bf16 (128B = 8 slots of 16B), both-sides
// XOR swizzle slot ^= (row&7) [rule #21: source pre-swizzled, read applies
// same involution; 8 lanes per slot-group = 2/bank = free per m136].
// BM=128: 4 waves 2x2, per-wave 64x64 (acc 4x4).  Tile N always 128.
// BM=64 : 4 waves 1x4, per-wave 64x32 (acc 4x2).
// ---------------------------------------------------------------------------
template <int BM, int OUT_BF16>
__device__ inline void gemm_body(const ushort_t* __restrict__ X,
                                 const ushort_t* __restrict__ W,
                                 const float* __restrict__ bias,
                                 ushort_t* __restrict__ outB,
                                 float* __restrict__ outF,
                                 int brow, int bcol) {
    __shared__ alignas(16) ushort_t As[BM * 64];
    __shared__ alignas(16) ushort_t Bs[128 * 64];
    constexpr int NJ = (BM == 128) ? 4 : 2;   // n-fragments per wave
    constexpr int AROWS = BM / 4;             // A rows staged per wave
    int tid = threadIdx.x;
    int lane = tid & 63, wid = tid >> 6;
    int WR = (BM == 128) ? (wid >> 1) : 0;
    int WC = (BM == 128) ? (wid & 1) : wid;

    f32x4 acc[4][NJ];
#pragma unroll
    for (int m = 0; m < 4; ++m)
#pragma unroll
        for (int n = 0; n < NJ; ++n)
            acc[m][n] = (f32x4){0.f, 0.f, 0.f, 0.f};

    int srow = lane >> 3;                       // 0..7
    int sslot = (lane & 7) ^ srow;              // logical k-slot to fetch
    int aRow0 = wid * AROWS;
    const ushort_t* aS = X + (size_t)(brow + aRow0 + srow) * DIM + sslot * 8;
    const ushort_t* bS = W + (size_t)(bcol + wid * 32 + srow) * DIM + sslot * 8;
    const ushort_t* ldsA = As + aRow0 * 64;
    const ushort_t* ldsB = Bs + wid * 32 * 64;

    int fr = lane & 15;
    int u = lane >> 4;
    const char* Ab = (const char*)As;
    const char* Bb = (const char*)Bs;

    for (int kc = 0; kc < DIM; kc += 64) {
        __syncthreads();
#pragma unroll
        for (int t = 0; t < AROWS / 8; ++t)
            gld16(aS + kc + (size_t)(8 * t) * DIM, ldsA + (8 * t) * 64);
#pragma unroll
        for (int t = 0; t < 4; ++t)
            gld16(bS + kc + (size_t)(8 * t) * DIM, ldsB + (8 * t) * 64);
        __syncthreads();
#pragma unroll
        for (int kk = 0; kk < 2; ++kk) {
            int slot = (kk * 4 + u) ^ (fr & 7);
            bf16x8 af[4], bfr[NJ];
#pragma unroll
            for (int m = 0; m < 4; ++m)
                af[m] = *(const bf16x8*)(Ab + (size_t)(WR * 64 + m * 16 + fr) * 128 + slot * 16);
#pragma unroll
            for (int n = 0; n < NJ; ++n)
                bfr[n] = *(const bf16x8*)(Bb + (size_t)(WC * (16 * NJ) + n * 16 + fr) * 128 + slot * 16);
#pragma unroll
            for (int m = 0; m < 4; ++m)
#pragma unroll
                for (int n = 0; n < NJ; ++n)
                    acc[m][n] = __builtin_amdgcn_mfma_f32_16x16x32_bf16(af[m], bfr[n], acc[m][n], 0, 0, 0);
        }
    }

#pragma unroll
    for (int m = 0; m < 4; ++m)
#pragma unroll
        for (int n = 0; n < NJ; ++n) {
            int col = bcol + WC * (16 * NJ) + n * 16 + (lane & 15);
            float bv = bias[col];
#pragma unroll
            for (int j = 0; j < 4; ++j) {
                int row = brow + WR * 64 + m * 16 + (lane >> 4) * 4 + j;
                float v = acc[m][n][j] + bv;
                if (OUT_BF16) outB[(size_t)row * DIM + col] = f2bf(v);
                else outF[(size_t)row * DIM + col] = v;
            }
        }
}

struct QKVArgs {
    const ushort_t* Xq;
    const ushort_t* Xkv;
    const ushort_t* W0; const ushort_t* W1; const ushort_t* W2;
    const float* b0; const float* b1; const float* b2;
    ushort_t* O0; ushort_t* O1; ushort_t* O2;
};

__global__ __launch_bounds__(256, 3) void qkv_gemm(QKVArgs a) {
    int z = blockIdx.z;
    const ushort_t* X = (z == 0) ? a.Xq : a.Xkv;
    const ushort_t* W = (z == 0) ? a.W0 : (z == 1) ? a.W1 : a.W2;
    const float* b = (z == 0) ? a.b0 : (z == 1) ? a.b1 : a.b2;
    ushort_t* O = (z == 0) ? a.O0 : (z == 1) ? a.O1 : a.O2;
    gemm_body<128, 1>(X, W, b, O, nullptr, blockIdx.x * 128, blockIdx.y * 128);
}

__global__ __launch_bounds__(256, 3) void o_gemm(const ushort_t* __restrict__ X,
                                                 const ushort_t* __restrict__ W,
                                                 const float* __restrict__ b,
                                                 float* __restrict__ Out) {
    gemm_body<64, 0>(X, W, b, nullptr, Out, blockIdx.x * 64, blockIdx.y * 128);
}

// ---------------------------------------------------------------------------
// MFMA segment attention. Grid (64 graphs, 8 heads), 4 waves per block.
// ---------------------------------------------------------------------------
#define MAXSEG 192
#define NKP 200   // padded key stride (elements); 400B rows -> ~2-way conflicts
__global__ __launch_bounds__(256) void attn_mfma(const ushort_t* __restrict__ Q,
                                                 const ushort_t* __restrict__ K,
                                                 const ushort_t* __restrict__ V,
                                                 ushort_t* __restrict__ M,
                                                 const int* __restrict__ seg,
                                                 int qbase, int kvbase) {
    __shared__ alignas(16) ushort_t VT[96 * NKP];        // V^T [dim][key]
    __shared__ alignas(16) ushort_t PL[4 * 16 * NKP];    // per-wave P [q][key]
    int b = blockIdx.x, h = blockIdx.y;
    int tid = threadIdx.x, lane = tid & 63, wid = tid >> 6;
    int qs = seg[qbase + b], qe = seg[qbase + 64 + b];
    int ks = seg[kvbase + b], ke = seg[kvbase + 64 + b];
    int nq = qe - qs, nk = ke - ks;
    if (nq <= 0) return;
    if (nk > MAXSEG) nk = MAXSEG;
    if (nk <= 0) {  // not expected for this dataset; zero the head slice
        for (int q = qs + wid; q < qe; q += 4)
            for (int c = lane; c < DH; c += 64)
                M[(size_t)q * DIM + h * DH + c] = 0;
        return;
    }
    int nkp32 = (nk + 31) & ~31;
    int nkt = nkp32 >> 4;   // 16-key score tiles
    int nk2 = nkp32 >> 5;   // 32-key PV steps

    // ---- stage V^T (zero-fill padded keys so 0*garbage can't be NaN) ----
    for (int idx = tid; idx < nkp32 * 12; idx += 256) {
        int j = idx / 12, c = idx - j * 12;     // key j, dim-octet c
        ushort_t tmp[8];
        if (j < nk) {
            *(uint4*)tmp = *(const uint4*)(V + (size_t)(ks + j) * DIM + h * DH + c * 8);
        } else {
#pragma unroll
            for (int r = 0; r < 8; ++r) tmp[r] = 0;
        }
#pragma unroll
        for (int r = 0; r < 8; ++r)
            VT[(size_t)(c * 8 + r) * NKP + j] = tmp[r];
    }
    __syncthreads();

    const float scale = 0.1020620726159658f;  // 1/sqrt(96)
    int fr = lane & 15;
    int koff = (lane >> 4) * 8;
    ushort_t* pl = PL + (size_t)wid * 16 * NKP;

    for (int qt = wid; qt * 16 < nq; qt += 4) {
        // ---- A-fragments of Q (clamped rows; masked at store) ----
        int qrow = qs + qt * 16 + fr;
        if (qrow > qe - 1) qrow = qe - 1;
        const ushort_t* qp = Q + (size_t)qrow * DIM + h * DH + koff;
        bf16x8 af0 = *(const bf16x8*)(qp);
        bf16x8 af1 = *(const bf16x8*)(qp + 32);
        bf16x8 af2 = *(const bf16x8*)(qp + 64);

        // ---- scores ----
        f32x4 sc[12];
#pragma unroll
        for (int kt = 0; kt < 12; ++kt) {
            if (kt >= nkt) continue;
            int key = ks + kt * 16 + fr;
            if (key > ke - 1) key = ke - 1;
            const ushort_t* kp = K + (size_t)key * DIM + h * DH + koff;
            f32x4 a = (f32x4){0.f, 0.f, 0.f, 0.f};
            a = __builtin_amdgcn_mfma_f32_16x16x32_bf16(af0, *(const bf16x8*)(kp), a, 0, 0, 0);
            a = __builtin_amdgcn_mfma_f32_16x16x32_bf16(af1, *(const bf16x8*)(kp + 32), a, 0, 0, 0);
            a = __builtin_amdgcn_mfma_f32_16x16x32_bf16(af2, *(const bf16x8*)(kp + 64), a, 0, 0, 0);
            sc[kt] = a;
        }

        // ---- softmax over keys (reduce across lane&15 within groups) ----
        float mrow[4] = {-1e30f, -1e30f, -1e30f, -1e30f};
#pragma unroll
        for (int kt = 0; kt < 12; ++kt) {
            if (kt >= nkt) continue;
            bool valid = (kt * 16 + fr) < nk;
#pragma unroll
            for (int j = 0; j < 4; ++j) {
                float s = valid ? sc[kt][j] * scale : -1e30f;
                sc[kt][j] = s;
                mrow[j] = fmaxf(mrow[j], s);
            }
        }
#pragma unroll
        for (int j = 0; j < 4; ++j) {
            mrow[j] = fmaxf(mrow[j], __shfl_xor(mrow[j], 1, 64));
            mrow[j] = fmaxf(mrow[j], __shfl_xor(mrow[j], 2, 64));
            mrow[j] = fmaxf(mrow[j], __shfl_xor(mrow[j], 4, 64));
            mrow[j] = fmaxf(mrow[j], __shfl_xor(mrow[j], 8, 64));
        }
        float rsum[4] = {0.f, 0.f, 0.f, 0.f};
#pragma unroll
        for (int kt = 0; kt < 12; ++kt) {
            if (kt >= nkt) continue;
#pragma unroll
            for (int j = 0; j < 4; ++j) {
                float p = __expf(sc[kt][j] - mrow[j]);
                sc[kt][j] = p;
                rsum[j] += p;
            }
        }
#pragma unroll
        for (int j = 0; j < 4; ++j) {
            rsum[j] += __shfl_xor(rsum[j], 1, 64);
            rsum[j] += __shfl_xor(rsum[j], 2, 64);
            rsum[j] += __shfl_xor(rsum[j], 4, 64);
            rsum[j] += __shfl_xor(rsum[j], 8, 64);
        }
        float rinv[4];
#pragma unroll
        for (int j = 0; j < 4; ++j) rinv[j] = 1.f / rsum[j];

        // ---- write P (bf16) to this wave's LDS tile ----
#pragma unroll
        for (int kt = 0; kt < 12; ++kt) {
            if (kt >= nkt) continue;
#pragma unroll
            for (int j = 0; j < 4; ++j)
                pl[(size_t)((lane >> 4) * 4 + j) * NKP + kt * 16 + fr] = f2bf(sc[kt][j]);
        }

        // ---- PV: out[q][d] tiles via MFMA, A from P_lds, B from VT ----
        f32x4 oacc[6];
#pragma unroll
        for (int nt = 0; nt < 6; ++nt) oacc[nt] = (f32x4){0.f, 0.f, 0.f, 0.f};
#pragma unroll
        for (int k2 = 0; k2 < 6; ++k2) {
            if (k2 >= nk2) continue;
            bf16x8 pa = *(const bf16x8*)(pl + (size_t)fr * NKP + k2 * 32 + koff);
#pragma unroll
            for (int nt = 0; nt < 6; ++nt) {
                bf16x8 vb = *(const bf16x8*)(VT + (size_t)(nt * 16 + fr) * NKP + k2 * 32 + koff);
                oacc[nt] = __builtin_amdgcn_mfma_f32_16x16x32_bf16(pa, vb, oacc[nt], 0, 0, 0);
            }
        }

        // ---- store head slice of M ----
#pragma unroll
        for (int nt = 0; nt < 6; ++nt)
#pragma unroll
            for (int j = 0; j < 4; ++j) {
                int qr = qt * 16 + (lane >> 4) * 4 + j;
                if (qr < nq)
                    M[(size_t)(qs + qr) * DIM + h * DH + nt * 16 + fr] = f2bf(oacc[nt][j] * rinv[j]);
            }
    }
}

// ---------------------------------------------------------------------------
// h = LayerNorm(h + o) * g + b  (in-place f32) + bf16 shadow
// One WAVE per row (4 rows/block), float4 loads, shfl-only reduce, no LDS.
// ---------------------------------------------------------------------------
__global__ __launch_bounds__(256) void add_ln_kernel(float* __restrict__ h,
                                                     ushort_t* __restrict__ hb,
                                                     const float* __restrict__ o,
                                                     const float* __restrict__ g,
                                                     const float* __restrict__ bb) {
    int row = blockIdx.x * 4 + (threadIdx.x >> 6);
    int lane = threadIdx.x & 63;
    float* hp = h + (size_t)row * DIM;
    const float* op = o + (size_t)row * DIM;
    float x[12];
    float s = 0.f, s2 = 0.f;
#pragma unroll
    for (int k = 0; k < 3; ++k) {
        int c = lane * 4 + k * 256;
        float4 a = *(const float4*)(hp + c);
        float4 bv = *(const float4*)(op + c);
        float v0 = a.x + bv.x, v1 = a.y + bv.y, v2 = a.z + bv.z, v3 = a.w + bv.w;
        x[4 * k + 0] = v0; x[4 * k + 1] = v1; x[4 * k + 2] = v2; x[4 * k + 3] = v3;
        s += (v0 + v1) + (v2 + v3);
        s2 += v0 * v0 + v1 * v1 + v2 * v2 + v3 * v3;
    }
#pragma unroll
    for (int off = 32; off; off >>= 1) {
        s += __shfl_xor(s, off, 64);
        s2 += __shfl_xor(s2, off, 64);
    }
    float mu = s * (1.f / 768.f);
    float var = s2 * (1.f / 768.f) - mu * mu;
    float rstd = rsqrtf(var + 1e-5f);
#pragma unroll
    for (int k = 0; k < 3; ++k) {
        int c = lane * 4 + k * 256;
        float4 gv = *(const float4*)(g + c);
        float4 bv = *(const float4*)(bb + c);
        float4 y;
        y.x = (x[4 * k + 0] - mu) * rstd * gv.x + bv.x;
        y.y = (x[4 * k + 1] - mu) * rstd * gv.y + bv.y;
        y.z = (x[4 * k + 2] - mu) * rstd * gv.z + bv.z;
        y.w = (x[4 * k + 3] - mu) * rstd * gv.w + bv.w;
        *(float4*)(hp + c) = y;
        uint2 p;
        p.x = (unsigned)f2bf(y.x) | ((unsigned)f2bf(y.y) << 16);
        p.y = (unsigned)f2bf(y.z) | ((unsigned)f2bf(y.w) << 16);
        *(uint2*)(hb + (size_t)row * DIM + c) = p;
    }
}

// ---------------------------------------------------------------------------
// Per-graph mean+max aggregate -> G[B, 1536]
// ---------------------------------------------------------------------------
__global__ __launch_bounds__(256) void agg_kernel(const float* __restrict__ h1,
                                                  const float* __restrict__ h2,
                                                  const int* __restrict__ seg,
                                                  float* __restrict__ G) {
    int b = blockIdx.x, side = blockIdx.y;
    int c = blockIdx.z * 256 + threadIdx.x;
    const float* hp = side ? h2 : h1;
    int s = seg[side * 128 + b], e = seg[side * 128 + 64 + b];
    int cnt = e - s;
    float sum = 0.f, mx = -1e30f;
    int i = s;
    for (; i + 4 <= e; i += 4) {
        float v0 = hp[(size_t)(i + 0) * DIM + c];
        float v1 = hp[(size_t)(i + 1) * DIM + c];
        float v2 = hp[(size_t)(i + 2) * DIM + c];
        float v3 = hp[(size_t)(i + 3) * DIM + c];
        sum += v0 + v1 + v2 + v3;
        mx = fmaxf(fmaxf(mx, fmaxf(v0, v1)), fmaxf(v2, v3));
    }
    for (; i < e; ++i) {
        float v = hp[(size_t)i * DIM + c];
        sum += v;
        mx = fmaxf(mx, v);
    }
    G[(size_t)b * 1536 + side * DIM + c] = (cnt > 0) ? (sum / (float)cnt + mx) : 0.f;
}

// ---------------------------------------------------------------------------
// Hid[b,j] = relu(G[b,:] @ W1[:,j] + b1[j]),  W1 in bf16.
// grid (16 b-groups of 4, 6 j-chunks of 128). Thread owns a j-quad
// (bf16x4 = 8B loads); 4 graphs amortize each W1 read; 8 waves k-split
// (192 each) + padded LDS reduce. 96 blocks, W1b traffic 37 MB total.
// ---------------------------------------------------------------------------
__global__ __launch_bounds__(256) void mlp1_kernel(const float* __restrict__ G,
                                                   const ushort_t* __restrict__ W1b,
                                                   const float* __restrict__ b1,
                                                   float* __restrict__ Hid) {
    __shared__ float gs[4][1536];
    __shared__ float red[7][32][17];    // [kq-1][jq][16 vals + pad]
    int bg = blockIdx.x;                // graphs bg*4 .. bg*4+3
    int jc = blockIdx.y;                // j chunk of 128
    int tid = threadIdx.x;
    int jq = tid & 31;                  // j-quad within chunk
    int kq = tid >> 5;                  // k eighth (192 rows)
    int j = jc * 128 + jq * 4;

    for (int idx = tid; idx < 4 * 1536 / 4; idx += 256)
        ((float4*)&gs[0][0])[idx] = ((const float4*)(G + (size_t)bg * 4 * 1536))[idx];
    __syncthreads();

    float acc[4][4] = {};
    const ushort_t* wp = W1b + (size_t)(kq * 192) * DIM + j;
    for (int i = 0; i < 192; ++i) {
        uint2 w = *(const uint2*)(wp + (size_t)i * DIM);
        float w0 = bf2f(w.x & 0xffffu), w1 = bf2f(w.x >> 16);
        float w2 = bf2f(w.y & 0xffffu), w3 = bf2f(w.y >> 16);
        int krow = kq * 192 + i;
#pragma unroll
        for (int bb = 0; bb < 4; ++bb) {
            float gv = gs[bb][krow];
            acc[bb][0] += gv * w0; acc[bb][1] += gv * w1;
            acc[bb][2] += gv * w2; acc[bb][3] += gv * w3;
        }
    }
    if (kq) {
#pragma unroll
        for (int bb = 0; bb < 4; ++bb)
#pragma unroll
            for (int c = 0; c < 4; ++c)
                red[kq - 1][jq][bb * 4 + c] = acc[bb][c];
    }
    __syncthreads();
    if (kq == 0) {
        float4 bv = *(const float4*)(b1 + j);
#pragma unroll
        for (int bb = 0; bb < 4; ++bb) {
            float r[4];
#pragma unroll
            for (int c = 0; c < 4; ++c) {
                r[c] = acc[bb][c];
#pragma unroll
                for (int q = 0; q < 7; ++q) r[c] += red[q][jq][bb * 4 + c];
            }
            float4 o;
            o.x = fmaxf(r[0] + bv.x, 0.f);
            o.y = fmaxf(r[1] + bv.y, 0.f);
            o.z = fmaxf(r[2] + bv.z, 0.f);
            o.w = fmaxf(r[3] + bv.w, 0.f);
            *(float4*)(Hid + (size_t)(bg * 4 + bb) * DIM + j) = o;
        }
    }
}

__global__ __launch_bounds__(256) void mlp2_kernel(const float* __restrict__ Hid,
                                                   const float* __restrict__ W2,
                                                   const float* __restrict__ b2,
                                                   float* __restrict__ out) {
    int b = blockIdx.x, tid = threadIdx.x;
    float s = 0.f;
    for (int j = tid; j < DIM; j += 256) s += Hid[(size_t)b * DIM + j] * W2[j];
#pragma unroll
    for (int off = 32; off; off >>= 1) s += __shfl_xor(s, off, 64);
    __shared__ float rs[4];
    if ((tid & 63) == 0) rs[tid >> 6] = s;
    __syncthreads();
    if (tid == 0) {
        float t = rs[0] + rs[1] + rs[2] + rs[3] + b2[0];
        out[b] = 1.f / (1.f + expf(-t));
    }
}

// ---------------------------------------------------------------------------
extern "C" void kernel_launch(void* const* d_in, const int* in_sizes, int n_in,
                              void* d_out, int out_size, void* d_ws, size_t ws_size,
                              hipStream_t stream) {
    const float* h1 = (const float*)d_in[0];
    const float* h2 = (const float*)d_in[1];
    const int* batch1 = (const int*)d_in[2];
    const int* batch2 = (const int*)d_in[3];
    const float* Wq = (const float*)d_in[4];
    const float* bq = (const float*)d_in[5];
    const float* Wk = (const float*)d_in[6];
    const float* bk = (const float*)d_in[7];
    const float* Wv = (const float*)d_in[8];
    const float* bv = (const float*)d_in[9];
    const float* Wo = (const float*)d_in[10];
    const float* bo = (const float*)d_in[11];
    const float* ln_g = (const float*)d_in[12];
    const float* ln_b = (const float*)d_in[13];
    const float* mW1 = (const float*)d_in[14];
    const float* mb1 = (const float*)d_in[15];
    const float* mW2 = (const float*)d_in[16];
    const float* mb2 = (const float*)d_in[17];
    float* out = (float*)d_out;

    const size_t ND = (size_t)N_NODES * DIM;        // 3145728
    const size_t WSZ = (size_t)DIM * DIM;           // 589824
    float* h1c = (float*)d_ws;
    float* h2c = h1c + ND;
    float* G = h2c + ND;
    float* Hid = G + 64 * 1536;
    ushort_t* h1b = (ushort_t*)(Hid + 64 * DIM);
    ushort_t* h2b = h1b + ND;
    ushort_t* Qb = h2b + ND;
    ushort_t* Kb = Qb + ND;
    ushort_t* Vb = Kb + ND;
    ushort_t* Mbb = Vb + ND;
    ushort_t* Wbt = Mbb + ND;                       // 8 matrices [N][K]
    ushort_t* W1bf = Wbt + 8 * WSZ;                 // mW1 bf16 [1536][768]
    int* seg = (int*)(W1bf + (size_t)1536 * DIM);
    float* Ob = (float*)Qb;  // aliases Qb+Kb (both dead when O-proj runs)

    cast_in2<<<dim3((int)(ND / 4 / 256), 2), 256, 0, stream>>>(h1, h2, h1c, h2c, h1b, h2b,
                                                               batch1, batch2, seg);
    wtcast_all<<<dim3(24, 24, 9), 256, 0, stream>>>(Wq, Wk, Wv, Wo, Wbt, mW1, W1bf);

    dim3 qkvg(32, 6, 3), og(64, 6), ag(64, 8);
    for (int i = 0; i < NL; ++i) {
        const ushort_t* wtq = Wbt + (0 * NL + i) * WSZ;
        const ushort_t* wtk = Wbt + (1 * NL + i) * WSZ;
        const ushort_t* wtv = Wbt + (2 * NL + i) * WSZ;
        const ushort_t* wto = Wbt + (3 * NL + i) * WSZ;
        const float* bqi = bq + (size_t)i * DIM;
        const float* bki = bk + (size_t)i * DIM;
        const float* bvi = bv + (size_t)i * DIM;
        const float* boi = bo + (size_t)i * DIM;

        // direction 1: queries h1, keys/values h2
        QKVArgs a1 = {h1b, h2b, wtq, wtk, wtv, bqi, bki, bvi, Qb, Kb, Vb};
        qkv_gemm<<<qkvg, 256, 0, stream>>>(a1);
        attn_mfma<<<ag, 256, 0, stream>>>(Qb, Kb, Vb, Mbb, seg, 0, 128);
        o_gemm<<<og, 256, 0, stream>>>(Mbb, wto, boi, Ob);
        add_ln_kernel<<<N_NODES / 4, 256, 0, stream>>>(h1c, h1b, Ob,
                                                       ln_g + (size_t)(2 * i) * DIM,
                                                       ln_b + (size_t)(2 * i) * DIM);

        // direction 2: queries h2, keys/values h1 (updated)
        QKVArgs a2 = {h2b, h1b, wtq, wtk, wtv, bqi, bki, bvi, Qb, Kb, Vb};
        qkv_gemm<<<qkvg, 256, 0, stream>>>(a2);
        attn_mfma<<<ag, 256, 0, stream>>>(Qb, Kb, Vb, Mbb, seg, 128, 0);
        o_gemm<<<og, 256, 0, stream>>>(Mbb, wto, boi, Ob);
        add_ln_kernel<<<N_NODES / 4, 256, 0, stream>>>(h2c, h2b, Ob,
                                                       ln_g + (size_t)(2 * i + 1) * DIM,
                                                       ln_b + (size_t)(2 * i + 1) * DIM);
    }
    agg_kernel<<<dim3(64, 2, 3), 256, 0, stream>>>(h1c, h2c, seg, G);
    mlp1_kernel<<<dim3(16, 6), 256, 0, stream>>>(G, W1bf, mb1, Hid);
    mlp2_kernel<<<64, 256, 0, stream>>>(Hid, mW2, mb2, out);
}